// Round 7
// baseline (427.824 us; speedup 1.0000x reference)
//
#include <hip/hip_runtime.h>

#define BATCH 4096
#define DM 768
#define LTOT 10240
#define NG 124

typedef __bf16 bf16x8 __attribute__((ext_vector_type(8)));
typedef short short8 __attribute__((ext_vector_type(8)));
typedef float f32x4 __attribute__((ext_vector_type(4)));

struct Ptr5 { const float* p[5]; };

__device__ __forceinline__ unsigned short f2bf(float f) {
    unsigned u = __builtin_bit_cast(unsigned, f);
    unsigned r = (u + 0x7FFFu + ((u >> 16) & 1u)) >> 16;   // RNE
    return (unsigned short)r;
}

// ---------------- fat prep kernel: conv V/U + gate, one dispatch ----------------
// Blocks 0..15359: conversion work (by=bx/1536: 0..4 V{g}, 5..9 U{g}).
// Blocks 15360..16383: gate rows (4 rows each). All paths independent:
// read-only inputs, disjoint outputs.

__global__ __launch_bounds__(256) void prep_k(const float* __restrict__ x,
                                              Ptr5 vp, Ptr5 up, Ptr5 ep, Ptr5 bp,
                                              unsigned short* __restrict__ vb,
                                              unsigned short* __restrict__ w2t,
                                              unsigned short* __restrict__ xb,
                                              float* __restrict__ gate_ws,
                                              float* __restrict__ outg,
                                              float* __restrict__ vn2,
                                              float* __restrict__ un2) {
    const int basen[5] = {0, 4, 12, 28, 60};
    int bx = blockIdx.x;
    int tid = threadIdx.x;
    if (bx < 15360) {
        // ---- conversion path ----
        __shared__ float sh[64];
        int which = bx / 1536;
        int isV = which < 5;
        int g = isV ? which : which - 5;
        int i = (bx - which * 1536) * 256 + tid;    // float4 index
        int idx = i * 4;
        int r = 512 >> g;
        const float* src = isV ? vp.p[g] : up.p[g];
        float4 v = ((const float4*)src)[i];
        ushort4 o;
        o.x = f2bf(v.x); o.y = f2bf(v.y); o.z = f2bf(v.z); o.w = f2bf(v.w);
        int nloc;
        if (isV) {
            ((ushort4*)(vb + (size_t)(g << 11) * DM))[i] = o;
            nloc = idx / (r * DM);
        } else {
            int lr = 9 - g;
            int rr = idx & (r - 1);
            int t2 = idx >> lr;            // n*768 + d
            int d  = t2 % DM;
            nloc   = t2 / DM;
            size_t dst = (size_t)d * LTOT + (size_t)(g << 11) + (size_t)nloc * r + rr;
            *(ushort4*)(w2t + dst) = o;
        }
        float s = v.x*v.x + v.y*v.y + v.z*v.z + v.w*v.w;
        if (tid < 64) sh[tid] = 0.f;
        __syncthreads();
        atomicAdd(&sh[nloc], s);
        __syncthreads();
        int ngc = 4 << g;
        float* dstN = isV ? vn2 : un2;
        if (tid < ngc && sh[tid] != 0.f)
            atomicAdd(&dstN[basen[g] + tid], sh[tid]);
    } else {
        // ---- gate path (fp32-exact) ----
        __shared__ float4 xs[4][193];
        int b0 = (bx - 15360) * 4;
        for (int i = tid; i < 4 * 192; i += 256) {
            int row = i / 192, c = i - row * 192;
            float4 v = ((const float4*)(x + (size_t)(b0 + row) * DM))[c];
            xs[row][c] = v;
            ushort4 o;
            o.x = f2bf(v.x); o.y = f2bf(v.y); o.z = f2bf(v.z); o.w = f2bf(v.w);
            ((ushort4*)xb)[(size_t)(b0 + row) * 192 + c] = o;
        }
        __syncthreads();
        if (tid < 248) {
            int n = tid >> 1;
            int rp = (tid & 1) * 2;
            int g = (n < 4) ? 0 : (n < 12) ? 1 : (n < 28) ? 2 : (n < 60) ? 3 : 4;
            int ni = n - basen[g];
            const float4* e4 = (const float4*)(ep.p[g] + (size_t)ni * DM);
            float a0 = 0.f, a1 = 0.f, a2 = 0.f, a3 = 0.f;
            float c0 = 0.f, c1 = 0.f, c2 = 0.f, c3 = 0.f;
            #pragma unroll 8
            for (int k = 0; k < 192; k++) {
                float4 ev = e4[k];
                float4 x0 = xs[rp][k];
                float4 x1 = xs[rp + 1][k];
                a0 = fmaf(x0.x, ev.x, a0); a1 = fmaf(x0.y, ev.y, a1);
                a2 = fmaf(x0.z, ev.z, a2); a3 = fmaf(x0.w, ev.w, a3);
                c0 = fmaf(x1.x, ev.x, c0); c1 = fmaf(x1.y, ev.y, c1);
                c2 = fmaf(x1.z, ev.z, c2); c3 = fmaf(x1.w, ev.w, c3);
            }
            float bias = bp.p[g][ni];
            float pre0 = (a0 + a1) + (a2 + a3) - bias;
            float pre1 = (c0 + c1) + (c2 + c3) - bias;
            float g0 = pre0 > 0.f ? pre0 : 0.f;
            float g1 = pre1 > 0.f ? pre1 : 0.f;
            int r0 = b0 + rp, r1 = b0 + rp + 1;
            gate_ws[(size_t)r0 * NG + n] = g0;
            gate_ws[(size_t)r1 * NG + n] = g1;
            const size_t baseg[5] = {3145730ull, 3145730ull + 16384, 3145730ull + 49152,
                                     3145730ull + 114688, 3145730ull + 245760};
            int w = 4 << g;
            outg[baseg[g] + (size_t)r0 * w + ni] = g0;
            outg[baseg[g] + (size_t)r1 * w + ni] = g1;
        }
    }
}

// ---------------- gate stats (coalesced column sums + active count) ----------------

__global__ __launch_bounds__(256) void gatestats_k(const float* __restrict__ gate_ws,
                                                   float* __restrict__ gate_sum,
                                                   float* __restrict__ active) {
    __shared__ float s0[124], s1[124];
    __shared__ unsigned cntsh;
    int tid = threadIdx.x;
    if (tid == 0) cntsh = 0u;
    int b0 = blockIdx.x * 32;               // grid = BATCH/32
    unsigned cl = 0;
    float s = 0.f;
    if (tid < 248) {
        int n = (tid < 124) ? tid : tid - 124;
        int rp = (tid < 124) ? 0 : 1;
        for (int r = rp; r < 32; r += 2) {
            float v = gate_ws[(size_t)(b0 + r) * NG + n];
            s += v;
            cl += (v > 0.f) ? 1u : 0u;
        }
        if (rp) s1[n] = s; else s0[n] = s;
    }
    if (cl) atomicAdd(&cntsh, cl);
    __syncthreads();
    if (tid < 124) {
        float t = s0[tid] + s1[tid];
        if (t != 0.f) atomicAdd(&gate_sum[tid], t);
    }
    if (tid == 0 && cntsh) atomicAdd(active, (float)cntsh);
}

// ---------------- MFMA GEMM (NT: C = A @ B^T) ----------------
// ROWSx64 bf16 tile staged via async global->LDS, 16B/lane.
// XOR swizzle: physical granule (row, kb^(row&7)) holds logical (row, kb).
template <int ROWS, int NT>
__device__ __forceinline__ void stage(const unsigned short* __restrict__ src, int ld,
                                      unsigned short* lds, int wv, int lane) {
    int rsub = lane >> 3;                      // 0..7: row within 8-row chunk
    int colb = ((lane ^ rsub) & 7) * 8;        // swizzled source granule
    #pragma unroll
    for (int i = 0; i < ROWS * 8 / NT; i++) {
        int c = i * (NT / 64) + wv;            // 512-elem chunk = 8 rows of 64 bf16
        const unsigned short* gp = src + (size_t)(c * 8 + rsub) * ld + colb;
        __builtin_amdgcn_global_load_lds((const __attribute__((address_space(1))) void*)gp,
                                         (__attribute__((address_space(3))) void*)(lds + c * 512),
                                         16, 0, 0);
    }
}

// EPI=0: gate + bf16 Hg via LDS-transposed wide-store epilogue.
// EPI=1: plain fp32 split-K partial stores (separate reduce kernel — fused
//        last-block reduce regressed 3x: device __threadfence drains the
//        non-coherent per-XCD L2s to HBM).
template <int BM, int BN, int EPI, int NT>
__global__ __launch_bounds__(NT) void gemm_nt(const unsigned short* __restrict__ A,
                                              const unsigned short* __restrict__ Bm,
                                              int Kblk, int lda, int ldb,
                                              void* __restrict__ Cout,
                                              const float* __restrict__ gate, int ldc) {
    __shared__ unsigned short lA[BM * 64];
    __shared__ unsigned short lB[BN * 64];
    int tid = threadIdx.x, wave = tid >> 6, lane = tid & 63;
    constexpr int WN = BN / 64;
    int wm = wave / WN, wn = wave % WN;
    int m0 = blockIdx.x * BM, n0 = blockIdx.y * BN;    // m is the FAST grid dim
    A  += (size_t)m0 * lda + (size_t)blockIdx.z * Kblk;
    Bm += (size_t)n0 * ldb + (size_t)blockIdx.z * Kblk;
    f32x4 acc[4][4] = {};
    int lan15 = lane & 15, quad = lane >> 4;
    int sw = lan15 & 7;                         // row&7 for all fragment rows

    for (int k0 = 0; k0 < Kblk; k0 += 64) {
        stage<BM, NT>(A + k0, lda, lA, wave, lane);
        stage<BN, NT>(Bm + k0, ldb, lB, wave, lane);
        __syncthreads();
        #pragma unroll
        for (int kk = 0; kk < 2; kk++) {
            int kb = kk * 4 + quad;             // logical 16B granule in K
            int kel = (kb ^ sw) * 8;            // swizzled element offset
            bf16x8 af[4], bfr[4];
            #pragma unroll
            for (int t = 0; t < 4; t++) {
                short8 ra = *(const short8*)(lA + (size_t)(wm * 64 + t * 16 + lan15) * 64 + kel);
                short8 rb = *(const short8*)(lB + (size_t)(wn * 64 + t * 16 + lan15) * 64 + kel);
                af[t]  = __builtin_bit_cast(bf16x8, ra);
                bfr[t] = __builtin_bit_cast(bf16x8, rb);
            }
            #pragma unroll
            for (int mt = 0; mt < 4; mt++)
                #pragma unroll
                for (int nt = 0; nt < 4; nt++)
                    acc[mt][nt] = __builtin_amdgcn_mfma_f32_16x16x32_bf16(af[mt], bfr[nt],
                                                                          acc[mt][nt], 0, 0, 0);
        }
        __syncthreads();
    }

    const int basen[5] = {0, 4, 12, 28, 60};
    if (EPI == 0) {
        // LDS-transposed epilogue: 4 phases (one per mt), each filling lA (16KB)
        // with the gated bf16 slab, then wide contiguous stores (512B runs/row).
        unsigned short* H = (unsigned short*)Cout;
        #pragma unroll
        for (int mt = 0; mt < 4; mt++) {
            __syncthreads();
            #pragma unroll
            for (int nt = 0; nt < 4; nt++) {
                int col = n0 + wn * 64 + nt * 16 + lan15;
                int g = col >> 11;
                int ngl = basen[g] + ((col & 2047) >> (9 - g));
                #pragma unroll
                for (int rg = 0; rg < 4; rg++) {
                    int grow = m0 + wm * 64 + mt * 16 + quad * 4 + rg;
                    float gv = gate[(size_t)grow * NG + ngl];
                    lA[wave * 1024 + (quad * 4 + rg) * 64 + nt * 16 + lan15] =
                        f2bf(acc[mt][nt][rg] * gv);
                }
            }
            __syncthreads();
            #pragma unroll
            for (int i = 0; i < 2; i++) {
                int f = i * NT + tid;           // 0..1023
                int R = f >> 5;                 // 0..31 (wm'*16 + r)
                int u = f & 31;                 // 16B col-chunk within 256
                int wv2 = ((R >> 4) << 2) + (u >> 3);
                short8 vread = *(const short8*)(lA + wv2 * 1024 + (R & 15) * 64 + (u & 7) * 8);
                int grow = m0 + (R >> 4) * 64 + mt * 16 + (R & 15);
                *(short8*)(H + (size_t)grow * ldc + n0 + u * 8) = vread;
            }
        }
    } else {
        float* P = (float*)Cout;
        P += (size_t)blockIdx.z * gridDim.x * BM * ldc;   // partial buffer for this z
        #pragma unroll
        for (int nt = 0; nt < 4; nt++) {
            int col = n0 + wn * 64 + nt * 16 + lan15;
            #pragma unroll
            for (int mt = 0; mt < 4; mt++) {
                int r0 = m0 + wm * 64 + mt * 16 + quad * 4;
                #pragma unroll
                for (int rg = 0; rg < 4; rg++)
                    P[(size_t)(r0 + rg) * ldc + col] = acc[mt][nt][rg];
            }
        }
    }
}

// ---------------- split-K reduce + fused final stats (block 0) ----------------

__global__ __launch_bounds__(256) void reduce_k(const float4* __restrict__ P,
                                                float4* __restrict__ out, int quarter,
                                                const float* __restrict__ st,
                                                float* __restrict__ o2) {
    int i = blockIdx.x * 256 + threadIdx.x;
    float4 a = P[i], b = P[i + quarter], c = P[i + 2 * quarter], d = P[i + 3 * quarter];
    float4 o;
    o.x = (a.x + b.x) + (c.x + d.x);
    o.y = (a.y + b.y) + (c.y + d.y);
    o.z = (a.z + b.z) + (c.z + d.z);
    o.w = (a.w + b.w) + (c.w + d.w);
    out[i] = o;
    if (blockIdx.x == 0) {
        // stats: st = [0,124) gate_sum, [124,248) un2, [248,372) vn2, [372] active
        __shared__ float sh[128];
        int t = threadIdx.x;
        if (t < 128) {
            float v = 0.f;
            if (t < NG) {
                int g = (t < 4) ? 0 : (t < 12) ? 1 : (t < 28) ? 2 : (t < 60) ? 3 : 4;
                float rr = (float)(512 >> g);
                float mean = st[t] * (1.0f / BATCH);
                float frob = sqrtf(st[124 + t] * st[248 + t]) / sqrtf(768.0f * rr);
                v = tanhf(mean) * frob;
            }
            sh[t] = v;
        }
        __syncthreads();
        for (int s = 64; s > 0; s >>= 1) {
            if (threadIdx.x < s) sh[threadIdx.x] += sh[threadIdx.x + s];
            __syncthreads();
        }
        if (threadIdx.x == 0) { o2[0] = sh[0]; o2[1] = st[372] * (1.0f / BATCH); }
    }
}

// ---------------- launcher ----------------

extern "C" void kernel_launch(void* const* d_in, const int* in_sizes, int n_in,
                              void* d_out, int out_size, void* d_ws, size_t ws_size,
                              hipStream_t stream) {
    const float* x = (const float*)d_in[0];
    Ptr5 vp, up, ep, bp;
    for (int g = 0; g < 5; g++) {
        vp.p[g] = (const float*)d_in[1 + 4 * g];
        up.p[g] = (const float*)d_in[2 + 4 * g];
        ep.p[g] = (const float*)d_in[3 + 4 * g];
        bp.p[g] = (const float*)d_in[4 + 4 * g];
    }
    float* out = (float*)d_out;
    char* ws = (char*)d_ws;
    size_t off = 0;
    unsigned short* xb  = (unsigned short*)(ws + off); off += (size_t)BATCH * DM * 2;
    unsigned short* vb  = (unsigned short*)(ws + off); off += (size_t)LTOT * DM * 2;
    unsigned short* w2t = (unsigned short*)(ws + off); off += (size_t)LTOT * DM * 2;
    float* gate_ws      = (float*)(ws + off);          off += (size_t)BATCH * NG * 4;
    float* stats        = (float*)(ws + off);          off += 4096;
    size_t fixed = off;
    int CB = BATCH;
    while (CB > 128 && fixed + (size_t)CB * LTOT * 2 + 4ull * CB * DM * 4 > ws_size) CB >>= 1;
    unsigned short* Hg  = (unsigned short*)(ws + fixed);
    float* partial      = (float*)(ws + fixed + (size_t)CB * LTOT * 2);

    hipMemsetAsync(stats, 0, 4096, stream);

    prep_k<<<dim3(15360 + BATCH / 4), 256, 0, stream>>>(
        x, vp, up, ep, bp, vb, w2t, xb, gate_ws, out, stats + 248, stats + 124);
    gatestats_k<<<dim3(BATCH / 32), 256, 0, stream>>>(gate_ws, stats, stats + 372);

    int nch = BATCH / CB;
    for (int c = 0; c < nch; c++) {
        // GEMM1: Hg = gate .* (x @ V^T)   (M=CB, N=10240, K=768), m-fast grid
        gemm_nt<128, 256, 0, 512><<<dim3(CB / 128, LTOT / 256, 1), 512, 0, stream>>>(
            xb + (size_t)c * CB * DM, vb, DM, DM, DM,
            (void*)Hg, gate_ws + (size_t)c * CB * NG, LTOT);
        // GEMM2: out = Hg @ W2   (M=CB, N=768, K=10240), split-K=4 partials
        gemm_nt<128, 128, 1, 256><<<dim3(CB / 128, DM / 128, 4), 256, 0, stream>>>(
            Hg, w2t, LTOT / 4, LTOT, LTOT,
            (void*)partial, nullptr, DM);
        // reduce + fused final stats (block 0)
        reduce_k<<<dim3(CB * 192 / 256), 256, 0, stream>>>(
            (const float4*)partial, (float4*)(out + (size_t)c * CB * DM), CB * DM / 4,
            stats, out + (size_t)BATCH * DM);
    }
}

// Round 8
// 366.048 us; speedup vs baseline: 1.1688x; 1.1688x over previous
//
#include <hip/hip_runtime.h>

#define BATCH 4096
#define DM 768
#define LTOT 10240
#define NG 124

typedef __bf16 bf16x8 __attribute__((ext_vector_type(8)));
typedef short short8 __attribute__((ext_vector_type(8)));
typedef float f32x4 __attribute__((ext_vector_type(4)));

struct Ptr5 { const float* p[5]; };

__device__ __forceinline__ unsigned short f2bf(float f) {
    unsigned u = __builtin_bit_cast(unsigned, f);
    unsigned r = (u + 0x7FFFu + ((u >> 16) & 1u)) >> 16;   // RNE
    return (unsigned short)r;
}

// ---------------- fat prep kernel ----------------
// bx [0,1024):        gate rows (4 rows/block) + xb cast  (heavy-latency work first)
// bx [1024,1984):     V{g} stream-cast, 2048 float4/block, one segment per block
// bx [1984,2944):     U{g} transpose-cast, same blocking
// Norm sums: registers -> wave shfl reduce -> ONE device atomic per block.

__global__ __launch_bounds__(256) void prep_k(const float* __restrict__ x,
                                              Ptr5 vp, Ptr5 up, Ptr5 ep, Ptr5 bp,
                                              unsigned short* __restrict__ vb,
                                              unsigned short* __restrict__ w2t,
                                              unsigned short* __restrict__ xb,
                                              float* __restrict__ gate_ws,
                                              float* __restrict__ outg,
                                              float* __restrict__ vn2,
                                              float* __restrict__ un2) {
    const int basen[5] = {0, 4, 12, 28, 60};
    int bx = blockIdx.x;
    int tid = threadIdx.x;
    if (bx < 1024) {
        // ---- gate path (fp32-exact) ----
        __shared__ float4 xs[4][193];
        int b0 = bx * 4;
        for (int i = tid; i < 4 * 192; i += 256) {
            int row = i / 192, c = i - row * 192;
            float4 v = ((const float4*)(x + (size_t)(b0 + row) * DM))[c];
            xs[row][c] = v;
            ushort4 o;
            o.x = f2bf(v.x); o.y = f2bf(v.y); o.z = f2bf(v.z); o.w = f2bf(v.w);
            ((ushort4*)xb)[(size_t)(b0 + row) * 192 + c] = o;
        }
        __syncthreads();
        if (tid < 248) {
            int n = tid >> 1;
            int rp = (tid & 1) * 2;
            int g = (n < 4) ? 0 : (n < 12) ? 1 : (n < 28) ? 2 : (n < 60) ? 3 : 4;
            int ni = n - basen[g];
            const float4* e4 = (const float4*)(ep.p[g] + (size_t)ni * DM);
            float a0 = 0.f, a1 = 0.f, a2 = 0.f, a3 = 0.f;
            float c0 = 0.f, c1 = 0.f, c2 = 0.f, c3 = 0.f;
            #pragma unroll 8
            for (int k = 0; k < 192; k++) {
                float4 ev = e4[k];
                float4 x0 = xs[rp][k];
                float4 x1 = xs[rp + 1][k];
                a0 = fmaf(x0.x, ev.x, a0); a1 = fmaf(x0.y, ev.y, a1);
                a2 = fmaf(x0.z, ev.z, a2); a3 = fmaf(x0.w, ev.w, a3);
                c0 = fmaf(x1.x, ev.x, c0); c1 = fmaf(x1.y, ev.y, c1);
                c2 = fmaf(x1.z, ev.z, c2); c3 = fmaf(x1.w, ev.w, c3);
            }
            float bias = bp.p[g][ni];
            float pre0 = (a0 + a1) + (a2 + a3) - bias;
            float pre1 = (c0 + c1) + (c2 + c3) - bias;
            float g0 = pre0 > 0.f ? pre0 : 0.f;
            float g1 = pre1 > 0.f ? pre1 : 0.f;
            int r0 = b0 + rp, r1 = b0 + rp + 1;
            gate_ws[(size_t)r0 * NG + n] = g0;
            gate_ws[(size_t)r1 * NG + n] = g1;
            const size_t baseg[5] = {3145730ull, 3145730ull + 16384, 3145730ull + 49152,
                                     3145730ull + 114688, 3145730ull + 245760};
            int w = 4 << g;
            outg[baseg[g] + (size_t)r0 * w + ni] = g0;
            outg[baseg[g] + (size_t)r1 * w + ni] = g1;
        }
    } else {
        // ---- streaming conversion path ----
        __shared__ float swave[4];
        int cb = bx - 1024;                 // 0..1919
        int isV = cb < 960;
        int wb = isV ? cb : cb - 960;       // 0..959
        int g = wb / 192;                   // 192 blocks per group (each group: 2048*768 floats)
        int within = wb - g * 192;          // block within group
        int bpseg = 48 >> g;                // blocks per n-segment
        int nloc = within / bpseg;          // n within group (uniform per block)
        const float* src = isV ? vp.p[g] : up.p[g];
        int r = 512 >> g, lr = 9 - g;
        float ss = 0.f;
        #pragma unroll
        for (int i = 0; i < 8; i++) {
            int j = within * 2048 + i * 256 + tid;       // float4 idx within group
            float4 v = ((const float4*)src)[j];
            ss += v.x*v.x + v.y*v.y + v.z*v.z + v.w*v.w;
            ushort4 o;
            o.x = f2bf(v.x); o.y = f2bf(v.y); o.z = f2bf(v.z); o.w = f2bf(v.w);
            if (isV) {
                ((ushort4*)vb)[(size_t)(g * 192 + within) * 2048 + i * 256 + tid] = o;
            } else {
                int idx = j * 4;
                int rr = idx & (r - 1);
                int t2 = idx >> lr;        // n*768 + d
                int d  = t2 % DM;
                int n  = t2 / DM;
                size_t dst = (size_t)d * LTOT + (size_t)(g << 11) + (size_t)n * r + rr;
                *(ushort4*)(w2t + dst) = o;
            }
        }
        // wave reduce then one atomic per block
        #pragma unroll
        for (int off = 32; off > 0; off >>= 1) ss += __shfl_down(ss, off);
        if ((tid & 63) == 0) swave[tid >> 6] = ss;
        __syncthreads();
        if (tid == 0) {
            float t = (swave[0] + swave[1]) + (swave[2] + swave[3]);
            float* dstN = isV ? vn2 : un2;
            atomicAdd(&dstN[basen[g] + nloc], t);
        }
    }
}

// ---------------- gate stats (coalesced column sums + active count) ----------------

__global__ __launch_bounds__(256) void gatestats_k(const float* __restrict__ gate_ws,
                                                   float* __restrict__ gate_sum,
                                                   float* __restrict__ active) {
    __shared__ float s0[124], s1[124];
    __shared__ unsigned cntsh;
    int tid = threadIdx.x;
    if (tid == 0) cntsh = 0u;
    int b0 = blockIdx.x * 32;               // grid = BATCH/32
    unsigned cl = 0;
    float s = 0.f;
    if (tid < 248) {
        int n = (tid < 124) ? tid : tid - 124;
        int rp = (tid < 124) ? 0 : 1;
        for (int r = rp; r < 32; r += 2) {
            float v = gate_ws[(size_t)(b0 + r) * NG + n];
            s += v;
            cl += (v > 0.f) ? 1u : 0u;
        }
        if (rp) s1[n] = s; else s0[n] = s;
    }
    if (cl) atomicAdd(&cntsh, cl);
    __syncthreads();
    if (tid < 124) {
        float t = s0[tid] + s1[tid];
        if (t != 0.f) atomicAdd(&gate_sum[tid], t);
    }
    if (tid == 0 && cntsh) atomicAdd(active, (float)cntsh);
}

// ---------------- MFMA GEMM (NT: C = A @ B^T) ----------------
// ROWSx64 bf16 tile staged via async global->LDS, 16B/lane.
// XOR swizzle: physical granule (row, kb^(row&7)) holds logical (row, kb).
template <int ROWS, int NT>
__device__ __forceinline__ void stage(const unsigned short* __restrict__ src, int ld,
                                      unsigned short* lds, int wv, int lane) {
    int rsub = lane >> 3;                      // 0..7: row within 8-row chunk
    int colb = ((lane ^ rsub) & 7) * 8;        // swizzled source granule
    #pragma unroll
    for (int i = 0; i < ROWS * 8 / NT; i++) {
        int c = i * (NT / 64) + wv;            // 512-elem chunk = 8 rows of 64 bf16
        const unsigned short* gp = src + (size_t)(c * 8 + rsub) * ld + colb;
        __builtin_amdgcn_global_load_lds((const __attribute__((address_space(1))) void*)gp,
                                         (__attribute__((address_space(3))) void*)(lds + c * 512),
                                         16, 0, 0);
    }
}

// EPI=0: gate + bf16 Hg via LDS-transposed wide-store epilogue.
// EPI=1: plain fp32 split-K partial stores (separate reduce kernel — fused
//        last-block reduce regressed 3x: device __threadfence drains the
//        non-coherent per-XCD L2s to HBM).
template <int BM, int BN, int EPI, int NT>
__global__ __launch_bounds__(NT) void gemm_nt(const unsigned short* __restrict__ A,
                                              const unsigned short* __restrict__ Bm,
                                              int Kblk, int lda, int ldb,
                                              void* __restrict__ Cout,
                                              const float* __restrict__ gate, int ldc) {
    __shared__ unsigned short lA[BM * 64];
    __shared__ unsigned short lB[BN * 64];
    int tid = threadIdx.x, wave = tid >> 6, lane = tid & 63;
    constexpr int WN = BN / 64;
    int wm = wave / WN, wn = wave % WN;
    int m0 = blockIdx.x * BM, n0 = blockIdx.y * BN;    // m is the FAST grid dim
    A  += (size_t)m0 * lda + (size_t)blockIdx.z * Kblk;
    Bm += (size_t)n0 * ldb + (size_t)blockIdx.z * Kblk;
    f32x4 acc[4][4] = {};
    int lan15 = lane & 15, quad = lane >> 4;
    int sw = lan15 & 7;                         // row&7 for all fragment rows

    for (int k0 = 0; k0 < Kblk; k0 += 64) {
        stage<BM, NT>(A + k0, lda, lA, wave, lane);
        stage<BN, NT>(Bm + k0, ldb, lB, wave, lane);
        __syncthreads();
        #pragma unroll
        for (int kk = 0; kk < 2; kk++) {
            int kb = kk * 4 + quad;             // logical 16B granule in K
            int kel = (kb ^ sw) * 8;            // swizzled element offset
            bf16x8 af[4], bfr[4];
            #pragma unroll
            for (int t = 0; t < 4; t++) {
                short8 ra = *(const short8*)(lA + (size_t)(wm * 64 + t * 16 + lan15) * 64 + kel);
                short8 rb = *(const short8*)(lB + (size_t)(wn * 64 + t * 16 + lan15) * 64 + kel);
                af[t]  = __builtin_bit_cast(bf16x8, ra);
                bfr[t] = __builtin_bit_cast(bf16x8, rb);
            }
            #pragma unroll
            for (int mt = 0; mt < 4; mt++)
                #pragma unroll
                for (int nt = 0; nt < 4; nt++)
                    acc[mt][nt] = __builtin_amdgcn_mfma_f32_16x16x32_bf16(af[mt], bfr[nt],
                                                                          acc[mt][nt], 0, 0, 0);
        }
        __syncthreads();
    }

    const int basen[5] = {0, 4, 12, 28, 60};
    if (EPI == 0) {
        // LDS-transposed epilogue: 4 phases (one per mt), each filling lA (16KB)
        // with the gated bf16 slab, then wide contiguous stores (512B runs/row).
        unsigned short* H = (unsigned short*)Cout;
        #pragma unroll
        for (int mt = 0; mt < 4; mt++) {
            __syncthreads();
            #pragma unroll
            for (int nt = 0; nt < 4; nt++) {
                int col = n0 + wn * 64 + nt * 16 + lan15;
                int g = col >> 11;
                int ngl = basen[g] + ((col & 2047) >> (9 - g));
                #pragma unroll
                for (int rg = 0; rg < 4; rg++) {
                    int grow = m0 + wm * 64 + mt * 16 + quad * 4 + rg;
                    float gv = gate[(size_t)grow * NG + ngl];
                    lA[wave * 1024 + (quad * 4 + rg) * 64 + nt * 16 + lan15] =
                        f2bf(acc[mt][nt][rg] * gv);
                }
            }
            __syncthreads();
            #pragma unroll
            for (int i = 0; i < 2; i++) {
                int f = i * NT + tid;           // 0..1023
                int R = f >> 5;                 // 0..31 (wm'*16 + r)
                int u = f & 31;                 // 16B col-chunk within 256
                int wv2 = ((R >> 4) << 2) + (u >> 3);
                short8 vread = *(const short8*)(lA + wv2 * 1024 + (R & 15) * 64 + (u & 7) * 8);
                int grow = m0 + (R >> 4) * 64 + mt * 16 + (R & 15);
                *(short8*)(H + (size_t)grow * ldc + n0 + u * 8) = vread;
            }
        }
    } else {
        float* P = (float*)Cout;
        P += (size_t)blockIdx.z * gridDim.x * BM * ldc;   // partial buffer for this z
        #pragma unroll
        for (int nt = 0; nt < 4; nt++) {
            int col = n0 + wn * 64 + nt * 16 + lan15;
            #pragma unroll
            for (int mt = 0; mt < 4; mt++) {
                int r0 = m0 + wm * 64 + mt * 16 + quad * 4;
                #pragma unroll
                for (int rg = 0; rg < 4; rg++)
                    P[(size_t)(r0 + rg) * ldc + col] = acc[mt][nt][rg];
            }
        }
    }
}

// ---------------- split-K reduce + fused final stats (block 0) ----------------

__global__ __launch_bounds__(256) void reduce_k(const float4* __restrict__ P,
                                                float4* __restrict__ out, int quarter,
                                                const float* __restrict__ st,
                                                float* __restrict__ o2) {
    int i = blockIdx.x * 256 + threadIdx.x;
    float4 a = P[i], b = P[i + quarter], c = P[i + 2 * quarter], d = P[i + 3 * quarter];
    float4 o;
    o.x = (a.x + b.x) + (c.x + d.x);
    o.y = (a.y + b.y) + (c.y + d.y);
    o.z = (a.z + b.z) + (c.z + d.z);
    o.w = (a.w + b.w) + (c.w + d.w);
    out[i] = o;
    if (blockIdx.x == 0) {
        // stats: st = [0,124) gate_sum, [124,248) un2, [248,372) vn2, [372] active
        __shared__ float sh[128];
        int t = threadIdx.x;
        if (t < 128) {
            float v = 0.f;
            if (t < NG) {
                int g = (t < 4) ? 0 : (t < 12) ? 1 : (t < 28) ? 2 : (t < 60) ? 3 : 4;
                float rr = (float)(512 >> g);
                float mean = st[t] * (1.0f / BATCH);
                float frob = sqrtf(st[124 + t] * st[248 + t]) / sqrtf(768.0f * rr);
                v = tanhf(mean) * frob;
            }
            sh[t] = v;
        }
        __syncthreads();
        for (int s = 64; s > 0; s >>= 1) {
            if (threadIdx.x < s) sh[threadIdx.x] += sh[threadIdx.x + s];
            __syncthreads();
        }
        if (threadIdx.x == 0) { o2[0] = sh[0]; o2[1] = st[372] * (1.0f / BATCH); }
    }
}

// ---------------- launcher ----------------

extern "C" void kernel_launch(void* const* d_in, const int* in_sizes, int n_in,
                              void* d_out, int out_size, void* d_ws, size_t ws_size,
                              hipStream_t stream) {
    const float* x = (const float*)d_in[0];
    Ptr5 vp, up, ep, bp;
    for (int g = 0; g < 5; g++) {
        vp.p[g] = (const float*)d_in[1 + 4 * g];
        up.p[g] = (const float*)d_in[2 + 4 * g];
        ep.p[g] = (const float*)d_in[3 + 4 * g];
        bp.p[g] = (const float*)d_in[4 + 4 * g];
    }
    float* out = (float*)d_out;
    char* ws = (char*)d_ws;
    size_t off = 0;
    unsigned short* xb  = (unsigned short*)(ws + off); off += (size_t)BATCH * DM * 2;
    unsigned short* vb  = (unsigned short*)(ws + off); off += (size_t)LTOT * DM * 2;
    unsigned short* w2t = (unsigned short*)(ws + off); off += (size_t)LTOT * DM * 2;
    float* gate_ws      = (float*)(ws + off);          off += (size_t)BATCH * NG * 4;
    float* stats        = (float*)(ws + off);          off += 4096;
    size_t fixed = off;
    int CB = BATCH;
    while (CB > 128 && fixed + (size_t)CB * LTOT * 2 + 4ull * CB * DM * 4 > ws_size) CB >>= 1;
    unsigned short* Hg  = (unsigned short*)(ws + fixed);
    float* partial      = (float*)(ws + fixed + (size_t)CB * LTOT * 2);

    hipMemsetAsync(stats, 0, 4096, stream);

    prep_k<<<dim3(1024 + 1920), 256, 0, stream>>>(
        x, vp, up, ep, bp, vb, w2t, xb, gate_ws, out, stats + 248, stats + 124);
    gatestats_k<<<dim3(BATCH / 32), 256, 0, stream>>>(gate_ws, stats, stats + 372);

    int nch = BATCH / CB;
    for (int c = 0; c < nch; c++) {
        // GEMM1: Hg = gate .* (x @ V^T)   (M=CB, N=10240, K=768), m-fast grid
        gemm_nt<128, 256, 0, 512><<<dim3(CB / 128, LTOT / 256, 1), 512, 0, stream>>>(
            xb + (size_t)c * CB * DM, vb, DM, DM, DM,
            (void*)Hg, gate_ws + (size_t)c * CB * NG, LTOT);
        // GEMM2: out = Hg @ W2   (M=CB, N=768, K=10240), split-K=4 partials
        gemm_nt<128, 128, 1, 256><<<dim3(CB / 128, DM / 128, 4), 256, 0, stream>>>(
            Hg, w2t, LTOT / 4, LTOT, LTOT,
            (void*)partial, nullptr, DM);
        // reduce + fused final stats (block 0)
        reduce_k<<<dim3(CB * 192 / 256), 256, 0, stream>>>(
            (const float4*)partial, (float4*)(out + (size_t)c * CB * DM), CB * DM / 4,
            stats, out + (size_t)BATCH * DM);
    }
}

// Round 9
// 337.899 us; speedup vs baseline: 1.2661x; 1.0833x over previous
//
#include <hip/hip_runtime.h>

#define BATCH 4096
#define DM 768
#define LTOT 10240
#define NG 124

typedef __bf16 bf16x8 __attribute__((ext_vector_type(8)));
typedef short short8 __attribute__((ext_vector_type(8)));
typedef float f32x4 __attribute__((ext_vector_type(4)));

struct Ptr5 { const float* p[5]; };

__device__ __forceinline__ unsigned short f2bf(float f) {
    unsigned u = __builtin_bit_cast(unsigned, f);
    unsigned r = (u + 0x7FFFu + ((u >> 16) & 1u)) >> 16;   // RNE
    return (unsigned short)r;
}

// ---------------- pure streaming prep kernel ----------------
// bx [0,1920):     V{g}/U{g} conv (2048 float4/block, one n-segment per block)
// bx [1920,2304):  x -> xb bf16 cast (2048 float4/block)
// bx [2304,2397):  enc -> encb bf16 (n-major 128x768, rows 124-127 unused)
// bx 2397:         biases -> b_all fp32[128]

__global__ __launch_bounds__(256) void prep_k(const float* __restrict__ x,
                                              Ptr5 vp, Ptr5 up, Ptr5 ep, Ptr5 bp,
                                              unsigned short* __restrict__ vb,
                                              unsigned short* __restrict__ w2t,
                                              unsigned short* __restrict__ xb,
                                              unsigned short* __restrict__ encb,
                                              float* __restrict__ b_all,
                                              float* __restrict__ vn2,
                                              float* __restrict__ un2) {
    const int basen[5] = {0, 4, 12, 28, 60};
    int bx = blockIdx.x;
    int tid = threadIdx.x;
    if (bx < 1920) {
        // ---- streaming V/U conversion + Frobenius norms ----
        __shared__ float swave[4];
        int isV = bx < 960;
        int wb = isV ? bx : bx - 960;       // 0..959
        int g = wb / 192;                   // 192 blocks per group
        int within = wb - g * 192;
        int bpseg = 48 >> g;                // blocks per n-segment
        int nloc = within / bpseg;
        const float* src = isV ? vp.p[g] : up.p[g];
        int r = 512 >> g, lr = 9 - g;
        float ss = 0.f;
        #pragma unroll
        for (int i = 0; i < 8; i++) {
            int j = within * 2048 + i * 256 + tid;       // float4 idx within group
            float4 v = ((const float4*)src)[j];
            ss += v.x*v.x + v.y*v.y + v.z*v.z + v.w*v.w;
            ushort4 o;
            o.x = f2bf(v.x); o.y = f2bf(v.y); o.z = f2bf(v.z); o.w = f2bf(v.w);
            if (isV) {
                ((ushort4*)vb)[(size_t)(g * 192 + within) * 2048 + i * 256 + tid] = o;
            } else {
                int idx = j * 4;
                int rr = idx & (r - 1);
                int t2 = idx >> lr;        // n*768 + d
                int d  = t2 % DM;
                int n  = t2 / DM;
                size_t dst = (size_t)d * LTOT + (size_t)(g << 11) + (size_t)n * r + rr;
                *(ushort4*)(w2t + dst) = o;
            }
        }
        #pragma unroll
        for (int off = 32; off > 0; off >>= 1) ss += __shfl_down(ss, off);
        if ((tid & 63) == 0) swave[tid >> 6] = ss;
        __syncthreads();
        if (tid == 0) {
            float t = (swave[0] + swave[1]) + (swave[2] + swave[3]);
            float* dstN = isV ? vn2 : un2;
            atomicAdd(&dstN[basen[g] + nloc], t);
        }
    } else if (bx < 2304) {
        // ---- x -> xb ----
        int base = (bx - 1920) * 2048;
        #pragma unroll
        for (int i = 0; i < 8; i++) {
            int j = base + i * 256 + tid;
            float4 v = ((const float4*)x)[j];
            ushort4 o;
            o.x = f2bf(v.x); o.y = f2bf(v.y); o.z = f2bf(v.z); o.w = f2bf(v.w);
            ((ushort4*)xb)[j] = o;
        }
    } else if (bx < 2397) {
        // ---- enc -> encb (n-major, ld=768) ----
        int j = (bx - 2304) * 256 + tid;    // float4 idx over 124*192
        int n = j / 192, c = j - n * 192;
        int g = (n < 4) ? 0 : (n < 12) ? 1 : (n < 28) ? 2 : (n < 60) ? 3 : 4;
        int ni = n - basen[g];
        float4 v = ((const float4*)ep.p[g])[ni * 192 + c];
        ushort4 o;
        o.x = f2bf(v.x); o.y = f2bf(v.y); o.z = f2bf(v.z); o.w = f2bf(v.w);
        ((ushort4*)encb)[n * 192 + c] = o;
    } else {
        // ---- biases ----
        if (tid < NG) {
            int n = tid;
            int g = (n < 4) ? 0 : (n < 12) ? 1 : (n < 28) ? 2 : (n < 60) ? 3 : 4;
            b_all[n] = bp.p[g][n - basen[g]];
        }
    }
}

// ---------------- gate stats (coalesced column sums + active count) ----------------

__global__ __launch_bounds__(256) void gatestats_k(const float* __restrict__ gate_ws,
                                                   float* __restrict__ gate_sum,
                                                   float* __restrict__ active) {
    __shared__ float s0[124], s1[124];
    __shared__ unsigned cntsh;
    int tid = threadIdx.x;
    if (tid == 0) cntsh = 0u;
    int b0 = blockIdx.x * 32;               // grid = BATCH/32
    unsigned cl = 0;
    float s = 0.f;
    if (tid < 248) {
        int n = (tid < 124) ? tid : tid - 124;
        int rp = (tid < 124) ? 0 : 1;
        for (int r = rp; r < 32; r += 2) {
            float v = gate_ws[(size_t)(b0 + r) * NG + n];
            s += v;
            cl += (v > 0.f) ? 1u : 0u;
        }
        if (rp) s1[n] = s; else s0[n] = s;
    }
    if (cl) atomicAdd(&cntsh, cl);
    __syncthreads();
    if (tid < 124) {
        float t = s0[tid] + s1[tid];
        if (t != 0.f) atomicAdd(&gate_sum[tid], t);
    }
    if (tid == 0 && cntsh) atomicAdd(active, (float)cntsh);
}

// ---------------- MFMA GEMM (NT: C = A @ B^T) ----------------
// ROWSx64 bf16 tile staged via async global->LDS, 16B/lane.
// XOR swizzle: physical granule (row, kb^(row&7)) holds logical (row, kb).
template <int ROWS, int NT>
__device__ __forceinline__ void stage(const unsigned short* __restrict__ src, int ld,
                                      unsigned short* lds, int wv, int lane) {
    int rsub = lane >> 3;                      // 0..7: row within 8-row chunk
    int colb = ((lane ^ rsub) & 7) * 8;        // swizzled source granule
    #pragma unroll
    for (int i = 0; i < ROWS * 8 / NT; i++) {
        int c = i * (NT / 64) + wv;            // 512-elem chunk = 8 rows of 64 bf16
        const unsigned short* gp = src + (size_t)(c * 8 + rsub) * ld + colb;
        __builtin_amdgcn_global_load_lds((const __attribute__((address_space(1))) void*)gp,
                                         (__attribute__((address_space(3))) void*)(lds + c * 512),
                                         16, 0, 0);
    }
}

// EPI=0: gate + bf16 Hg via LDS-transposed wide-store epilogue.
// EPI=1: plain fp32 split-K partial stores (separate reduce kernel — fused
//        last-block reduce regressed 3x: device __threadfence drains the
//        non-coherent per-XCD L2s to HBM).
// EPI=2: gate pre-activation GEMM: relu(acc - bias[col]) -> gate_ws + outg copies.
template <int BM, int BN, int EPI, int NT>
__global__ __launch_bounds__(NT) void gemm_nt(const unsigned short* __restrict__ A,
                                              const unsigned short* __restrict__ Bm,
                                              int Kblk, int lda, int ldb,
                                              void* __restrict__ Cout,
                                              const float* __restrict__ gate, int ldc,
                                              float* __restrict__ extra) {
    __shared__ unsigned short lA[BM * 64];
    __shared__ unsigned short lB[BN * 64];
    int tid = threadIdx.x, wave = tid >> 6, lane = tid & 63;
    constexpr int WN = BN / 64;
    int wm = wave / WN, wn = wave % WN;
    int m0 = blockIdx.x * BM, n0 = blockIdx.y * BN;    // m is the FAST grid dim
    A  += (size_t)m0 * lda + (size_t)blockIdx.z * Kblk;
    Bm += (size_t)n0 * ldb + (size_t)blockIdx.z * Kblk;
    f32x4 acc[4][4] = {};
    int lan15 = lane & 15, quad = lane >> 4;
    int sw = lan15 & 7;                         // row&7 for all fragment rows

    for (int k0 = 0; k0 < Kblk; k0 += 64) {
        stage<BM, NT>(A + k0, lda, lA, wave, lane);
        stage<BN, NT>(Bm + k0, ldb, lB, wave, lane);
        __syncthreads();
        #pragma unroll
        for (int kk = 0; kk < 2; kk++) {
            int kb = kk * 4 + quad;             // logical 16B granule in K
            int kel = (kb ^ sw) * 8;            // swizzled element offset
            bf16x8 af[4], bfr[4];
            #pragma unroll
            for (int t = 0; t < 4; t++) {
                short8 ra = *(const short8*)(lA + (size_t)(wm * 64 + t * 16 + lan15) * 64 + kel);
                short8 rb = *(const short8*)(lB + (size_t)(wn * 64 + t * 16 + lan15) * 64 + kel);
                af[t]  = __builtin_bit_cast(bf16x8, ra);
                bfr[t] = __builtin_bit_cast(bf16x8, rb);
            }
            #pragma unroll
            for (int mt = 0; mt < 4; mt++)
                #pragma unroll
                for (int nt = 0; nt < 4; nt++)
                    acc[mt][nt] = __builtin_amdgcn_mfma_f32_16x16x32_bf16(af[mt], bfr[nt],
                                                                          acc[mt][nt], 0, 0, 0);
        }
        __syncthreads();
    }

    const int basen[5] = {0, 4, 12, 28, 60};
    if (EPI == 0) {
        // LDS-transposed epilogue: 4 phases (one per mt), each filling lA (16KB)
        // with the gated bf16 slab, then wide contiguous stores (512B runs/row).
        unsigned short* H = (unsigned short*)Cout;
        #pragma unroll
        for (int mt = 0; mt < 4; mt++) {
            __syncthreads();
            #pragma unroll
            for (int nt = 0; nt < 4; nt++) {
                int col = n0 + wn * 64 + nt * 16 + lan15;
                int g = col >> 11;
                int ngl = basen[g] + ((col & 2047) >> (9 - g));
                #pragma unroll
                for (int rg = 0; rg < 4; rg++) {
                    int grow = m0 + wm * 64 + mt * 16 + quad * 4 + rg;
                    float gv = gate[(size_t)grow * NG + ngl];
                    lA[wave * 1024 + (quad * 4 + rg) * 64 + nt * 16 + lan15] =
                        f2bf(acc[mt][nt][rg] * gv);
                }
            }
            __syncthreads();
            #pragma unroll
            for (int i = 0; i < 2; i++) {
                int f = i * NT + tid;           // 0..1023
                int R = f >> 5;                 // 0..31 (wm'*16 + r)
                int u = f & 31;                 // 16B col-chunk within 256
                int wv2 = ((R >> 4) << 2) + (u >> 3);
                short8 vread = *(const short8*)(lA + wv2 * 1024 + (R & 15) * 64 + (u & 7) * 8);
                int grow = m0 + (R >> 4) * 64 + mt * 16 + (R & 15);
                *(short8*)(H + (size_t)grow * ldc + n0 + u * 8) = vread;
            }
        }
    } else if (EPI == 1) {
        float* P = (float*)Cout;
        P += (size_t)blockIdx.z * gridDim.x * BM * ldc;   // partial buffer for this z
        #pragma unroll
        for (int nt = 0; nt < 4; nt++) {
            int col = n0 + wn * 64 + nt * 16 + lan15;
            #pragma unroll
            for (int mt = 0; mt < 4; mt++) {
                int r0 = m0 + wm * 64 + mt * 16 + quad * 4;
                #pragma unroll
                for (int rg = 0; rg < 4; rg++)
                    P[(size_t)(r0 + rg) * ldc + col] = acc[mt][nt][rg];
            }
        }
    } else {
        // gate epilogue: cols are global n indices (n0==0, BN=128, valid < 124)
        float* GW = (float*)Cout;               // gate_ws, ld = ldc (=NG)
        float* OG = extra;                      // d_out gate region base
        const size_t baseg[5] = {3145730ull, 3145730ull + 16384, 3145730ull + 49152,
                                 3145730ull + 114688, 3145730ull + 245760};
        #pragma unroll
        for (int nt = 0; nt < 4; nt++) {
            int col = wn * 64 + nt * 16 + lan15;
            if (col < NG) {
                int g = (col < 4) ? 0 : (col < 12) ? 1 : (col < 28) ? 2 : (col < 60) ? 3 : 4;
                int ni = col - basen[g];
                int w = 4 << g;
                float bv = gate[col];           // bias vector
                #pragma unroll
                for (int mt = 0; mt < 4; mt++) {
                    int r0 = m0 + wm * 64 + mt * 16 + quad * 4;
                    #pragma unroll
                    for (int rg = 0; rg < 4; rg++) {
                        float pre = acc[mt][nt][rg] - bv;
                        float gt = pre > 0.f ? pre : 0.f;
                        GW[(size_t)(r0 + rg) * ldc + col] = gt;
                        OG[baseg[g] + (size_t)(r0 + rg) * w + ni] = gt;
                    }
                }
            }
        }
    }
}

// ---------------- split-K reduce + fused final stats (block 0) ----------------

__global__ __launch_bounds__(256) void reduce_k(const float4* __restrict__ P,
                                                float4* __restrict__ out, int quarter,
                                                const float* __restrict__ st,
                                                float* __restrict__ o2) {
    int i = blockIdx.x * 256 + threadIdx.x;
    float4 a = P[i], b = P[i + quarter], c = P[i + 2 * quarter], d = P[i + 3 * quarter];
    float4 o;
    o.x = (a.x + b.x) + (c.x + d.x);
    o.y = (a.y + b.y) + (c.y + d.y);
    o.z = (a.z + b.z) + (c.z + d.z);
    o.w = (a.w + b.w) + (c.w + d.w);
    out[i] = o;
    if (blockIdx.x == 0) {
        // stats: st = [0,124) gate_sum, [124,248) un2, [248,372) vn2, [372] active
        __shared__ float sh[128];
        int t = threadIdx.x;
        if (t < 128) {
            float v = 0.f;
            if (t < NG) {
                int g = (t < 4) ? 0 : (t < 12) ? 1 : (t < 28) ? 2 : (t < 60) ? 3 : 4;
                float rr = (float)(512 >> g);
                float mean = st[t] * (1.0f / BATCH);
                float frob = sqrtf(st[124 + t] * st[248 + t]) / sqrtf(768.0f * rr);
                v = tanhf(mean) * frob;
            }
            sh[t] = v;
        }
        __syncthreads();
        for (int s = 64; s > 0; s >>= 1) {
            if (threadIdx.x < s) sh[threadIdx.x] += sh[threadIdx.x + s];
            __syncthreads();
        }
        if (threadIdx.x == 0) { o2[0] = sh[0]; o2[1] = st[372] * (1.0f / BATCH); }
    }
}

// ---------------- launcher ----------------

extern "C" void kernel_launch(void* const* d_in, const int* in_sizes, int n_in,
                              void* d_out, int out_size, void* d_ws, size_t ws_size,
                              hipStream_t stream) {
    const float* x = (const float*)d_in[0];
    Ptr5 vp, up, ep, bp;
    for (int g = 0; g < 5; g++) {
        vp.p[g] = (const float*)d_in[1 + 4 * g];
        up.p[g] = (const float*)d_in[2 + 4 * g];
        ep.p[g] = (const float*)d_in[3 + 4 * g];
        bp.p[g] = (const float*)d_in[4 + 4 * g];
    }
    float* out = (float*)d_out;
    char* ws = (char*)d_ws;
    size_t off = 0;
    unsigned short* xb   = (unsigned short*)(ws + off); off += (size_t)BATCH * DM * 2;
    unsigned short* vb   = (unsigned short*)(ws + off); off += (size_t)LTOT * DM * 2;
    unsigned short* w2t  = (unsigned short*)(ws + off); off += (size_t)LTOT * DM * 2;
    unsigned short* encb = (unsigned short*)(ws + off); off += (size_t)128 * DM * 2;
    float* b_all         = (float*)(ws + off);          off += 512;
    float* gate_ws       = (float*)(ws + off);          off += (size_t)BATCH * NG * 4;
    float* stats         = (float*)(ws + off);          off += 4096;
    size_t fixed = off;
    int CB = BATCH;
    while (CB > 128 && fixed + (size_t)CB * LTOT * 2 + 4ull * CB * DM * 4 > ws_size) CB >>= 1;
    unsigned short* Hg  = (unsigned short*)(ws + fixed);
    float* partial      = (float*)(ws + fixed + (size_t)CB * LTOT * 2);

    hipMemsetAsync(stats, 0, 4096, stream);

    prep_k<<<dim3(2398), 256, 0, stream>>>(
        x, vp, up, ep, bp, vb, w2t, xb, encb, b_all, stats + 248, stats + 124);
    // gate GEMM: pre = xb @ encb^T  (M=4096, N=128(124), K=768) -> relu - bias
    gemm_nt<128, 128, 2, 256><<<dim3(BATCH / 128, 1, 1), 256, 0, stream>>>(
        xb, encb, DM, DM, DM, (void*)gate_ws, b_all, NG, out);
    gatestats_k<<<dim3(BATCH / 32), 256, 0, stream>>>(gate_ws, stats, stats + 372);

    int nch = BATCH / CB;
    for (int c = 0; c < nch; c++) {
        // GEMM1: Hg = gate .* (x @ V^T)   (M=CB, N=10240, K=768), m-fast grid
        gemm_nt<128, 256, 0, 512><<<dim3(CB / 128, LTOT / 256, 1), 512, 0, stream>>>(
            xb + (size_t)c * CB * DM, vb, DM, DM, DM,
            (void*)Hg, gate_ws + (size_t)c * CB * NG, LTOT, nullptr);
        // GEMM2: out = Hg @ W2   (M=CB, N=768, K=10240), split-K=4 partials
        gemm_nt<128, 128, 1, 256><<<dim3(CB / 128, DM / 128, 4), 256, 0, stream>>>(
            Hg, w2t, LTOT / 4, LTOT, LTOT,
            (void*)partial, nullptr, DM, nullptr);
        // reduce + fused final stats (block 0)
        reduce_k<<<dim3(CB * 192 / 256), 256, 0, stream>>>(
            (const float4*)partial, (float4*)(out + (size_t)c * CB * DM), CB * DM / 4,
            stats, out + (size_t)BATCH * DM);
    }
}